// Round 2
// baseline (123.163 us; speedup 1.0000x reference)
//
#include <hip/hip_runtime.h>
#include <hip/hip_bf16.h>

#define B_DIM 4
#define C_DIM 256
#define N_DIM 4096
#define NBLK  128   // N_DIM / 32

typedef unsigned short ushort8 __attribute__((ext_vector_type(8)));
typedef short          short8  __attribute__((ext_vector_type(8)));
typedef float          f32x4   __attribute__((ext_vector_type(4)));

__device__ __forceinline__ unsigned short f2bf(float x) {
    __hip_bfloat16 h = __float2bfloat16(x);
    return __builtin_bit_cast(unsigned short, h);
}
__device__ __forceinline__ float b2f(unsigned short u) {
    return __builtin_bit_cast(float, (unsigned)u << 16);
}
__device__ __forceinline__ unsigned pack2(float a, float b) {
    return (unsigned)f2bf(a) | ((unsigned)f2bf(b) << 16);
}

// ---------------------------------------------------------------------------
// castW: W fp32 [r][c] -> bf16 [r][c]; 1/sqrt(256) folded into Wk.  64 blocks.
// ---------------------------------------------------------------------------
__global__ __launch_bounds__(256) void castW(
    const float* __restrict__ Wk, const float* __restrict__ Wv,
    unsigned short* __restrict__ Wkb, unsigned short* __restrict__ Wvb)
{
    const int bid = blockIdx.x;
    const int mat = bid >> 5;           // 0: Wk, 1: Wv
    const float* src = mat ? Wv : Wk;
    unsigned short* dst = mat ? Wvb : Wkb;
    const float scale = mat ? 1.0f : 0.0625f;
    int idx = (bid & 31) * 2048 + threadIdx.x * 8;
    float4 f0 = *(const float4*)(src + idx);
    float4 f1 = *(const float4*)(src + idx + 4);
    ushort8 u;
    u[0] = f2bf(f0.x * scale); u[1] = f2bf(f0.y * scale);
    u[2] = f2bf(f0.z * scale); u[3] = f2bf(f0.w * scale);
    u[4] = f2bf(f1.x * scale); u[5] = f2bf(f1.y * scale);
    u[6] = f2bf(f1.z * scale); u[7] = f2bf(f1.w * scale);
    *(ushort8*)(dst + idx) = u;
}

// ---------------------------------------------------------------------------
// kvsb: one block per (b, 32-col tile).  512 thr = 8 waves, 2 blocks/CU.
//  P1: X[256c][48n halo] f32 -> bf16 XB_lds (transposed, [nloc][c]); H prefetch.
//  P2: GEMM.  K-waves (wid<4): K = Wk·x, 48 cols -> Kl_lds bf16 [nloc][r].
//             V-waves: V = Wv·x, 48 cols -> packed regs -> V2_lds (over XB).
//  P3: scores s[n,dd] for n in [n0-2, n0+34) (36 cols; 4 halo cols done by
//      64 doubled-up threads) from Kl + registered H.
//  P4-P6: reduce, exp, denominators, band weights ew[ddp][mloc] -- all LDS.
//  P7: Out = x + band (direct), plus per-block colsum partial Sp[b][blk][c].
//  K, V, EWT never touch global memory.
// ---------------------------------------------------------------------------
__global__ __launch_bounds__(512, 4) void kvsb(
    const float* __restrict__ X,
    const unsigned short* __restrict__ Wkb,
    const unsigned short* __restrict__ Wvb,
    const float* __restrict__ H,
    float* __restrict__ Out,
    float* __restrict__ Sp)
{
    __shared__ __align__(16) unsigned short AB[48][264];  // XB, then V2
    __shared__ __align__(16) unsigned short Kl[48][264];  // K bf16 [nloc][r]
    __shared__ float sacc[16][5][36];
    __shared__ float se[5][36];
    __shared__ float sw[36];
    __shared__ float ew[5][32];

    const int b   = blockIdx.y;
    const int n0  = blockIdx.x * 32;
    const int tid = threadIdx.x;
    const int lane = tid & 63, wid = tid >> 6;
    const int ln = lane & 15, q = lane >> 4;
    const int nl = tid & 31, ch = tid >> 5;          // scores: 16 ch x 32 nl

    // ---- P1: H prefetch (consumed in P3) + X tile -> XB ----
    const float* Hb = H + ((size_t)(b * C_DIM + ch * 16)) * N_DIM + n0 + nl;
    float Hp[16];
    #pragma unroll
    for (int t = 0; t < 16; ++t) Hp[t] = Hb[(size_t)t * N_DIM];

    {
        const int cx = tid >> 1, half = tid & 1;
        const float* xs = X + ((size_t)(b * C_DIM + cx)) * N_DIM;
        const int nb = n0 - 8 + half * 24;
        float xv[24];
        if (blockIdx.x == 0 || blockIdx.x == NBLK - 1) {
            #pragma unroll
            for (int j = 0; j < 24; ++j) {
                int ns = nb + j;
                ns = ns < 0 ? 0 : (ns > N_DIM - 1 ? N_DIM - 1 : ns);
                xv[j] = xs[ns];
            }
        } else {
            #pragma unroll
            for (int g = 0; g < 6; ++g) {
                float4 f = *(const float4*)(xs + nb + g * 4);
                xv[g*4+0] = f.x; xv[g*4+1] = f.y;
                xv[g*4+2] = f.z; xv[g*4+3] = f.w;
            }
        }
        #pragma unroll
        for (int j = 0; j < 24; ++j)
            AB[half * 24 + j][cx] = f2bf(xv[j]);
    }
    __syncthreads();   // B1: XB ready

    // ---- P2: GEMM (A = W rows from global L2, B = XB from LDS) ----
    const int rbase = (wid & 3) * 64;
    const unsigned short* Wb_ = (wid < 4) ? Wkb : Wvb;
    const unsigned short* pa = Wb_ + (size_t)(rbase + ln) * C_DIM + q * 8;

    f32x4 acc[4][3] = {};
    #pragma unroll
    for (int c0 = 0; c0 < C_DIM; c0 += 32) {
        short8 A0 = *(const short8*)(pa + c0);
        short8 A1 = *(const short8*)(pa + 16 * C_DIM + c0);
        short8 A2 = *(const short8*)(pa + 32 * C_DIM + c0);
        short8 A3 = *(const short8*)(pa + 48 * C_DIM + c0);
        short8 B0 = *(const short8*)&AB[ln     ][c0 + q * 8];
        short8 B1 = *(const short8*)&AB[16 + ln][c0 + q * 8];
        short8 B2 = *(const short8*)&AB[32 + ln][c0 + q * 8];
        acc[0][0] = __builtin_amdgcn_mfma_f32_16x16x32_bf16(A0, B0, acc[0][0], 0, 0, 0);
        acc[1][0] = __builtin_amdgcn_mfma_f32_16x16x32_bf16(A1, B0, acc[1][0], 0, 0, 0);
        acc[2][0] = __builtin_amdgcn_mfma_f32_16x16x32_bf16(A2, B0, acc[2][0], 0, 0, 0);
        acc[3][0] = __builtin_amdgcn_mfma_f32_16x16x32_bf16(A3, B0, acc[3][0], 0, 0, 0);
        acc[0][1] = __builtin_amdgcn_mfma_f32_16x16x32_bf16(A0, B1, acc[0][1], 0, 0, 0);
        acc[1][1] = __builtin_amdgcn_mfma_f32_16x16x32_bf16(A1, B1, acc[1][1], 0, 0, 0);
        acc[2][1] = __builtin_amdgcn_mfma_f32_16x16x32_bf16(A2, B1, acc[2][1], 0, 0, 0);
        acc[3][1] = __builtin_amdgcn_mfma_f32_16x16x32_bf16(A3, B1, acc[3][1], 0, 0, 0);
        acc[0][2] = __builtin_amdgcn_mfma_f32_16x16x32_bf16(A0, B2, acc[0][2], 0, 0, 0);
        acc[1][2] = __builtin_amdgcn_mfma_f32_16x16x32_bf16(A1, B2, acc[1][2], 0, 0, 0);
        acc[2][2] = __builtin_amdgcn_mfma_f32_16x16x32_bf16(A2, B2, acc[2][2], 0, 0, 0);
        acc[3][2] = __builtin_amdgcn_mfma_f32_16x16x32_bf16(A3, B2, acc[3][2], 0, 0, 0);
    }

    unsigned vpk[12][2];
    if (wid < 4) {
        // K -> Kl bf16.  4 regs = 4 consecutive r -> one 8-byte store.
        #pragma unroll
        for (int j = 0; j < 3; ++j)
            #pragma unroll
            for (int i = 0; i < 4; ++i) {
                unsigned* p = (unsigned*)&Kl[j * 16 + ln][rbase + i * 16 + q * 4];
                p[0] = pack2(acc[i][j][0], acc[i][j][1]);
                p[1] = pack2(acc[i][j][2], acc[i][j][3]);
            }
    } else {
        // V: pack to regs now (frees 24 VGPR through scores phase).
        #pragma unroll
        for (int j = 0; j < 3; ++j)
            #pragma unroll
            for (int i = 0; i < 4; ++i) {
                vpk[j*4+i][0] = pack2(acc[i][j][0], acc[i][j][1]);
                vpk[j*4+i][1] = pack2(acc[i][j][2], acc[i][j][3]);
            }
    }
    __syncthreads();   // B2: Kl ready, XB dead

    // ---- P3: V-waves store V2 over XB; everyone does scores ----
    if (wid >= 4) {
        #pragma unroll
        for (int j = 0; j < 3; ++j)
            #pragma unroll
            for (int i = 0; i < 4; ++i) {
                unsigned* p = (unsigned*)&AB[j * 16 + ln][rbase + i * 16 + q * 4];
                p[0] = vpk[j*4+i][0];
                p[1] = vpk[j*4+i][1];
            }
    }
    // halo-column H loads (issued early to overlap main scores FMAs)
    float He[16];
    int jx = 0;
    if (tid < 64) {
        const int ch2 = tid >> 2, je = tid & 3;
        jx = je < 2 ? je : je + 32;                  // j in {0,1,34,35}
        int ncol = n0 - 2 + jx;
        ncol = ncol < 0 ? 0 : (ncol > N_DIM - 1 ? N_DIM - 1 : ncol);
        const float* Hx = H + ((size_t)(b * C_DIM + ch2 * 16)) * N_DIM + ncol;
        #pragma unroll
        for (int t = 0; t < 16; ++t) He[t] = Hx[(size_t)t * N_DIM];
    }
    // main scores: slot j = nl + 2  (n = n0 + nl)
    #pragma unroll
    for (int dd = 0; dd < 5; ++dd) {
        const short8 k0 = *(const short8*)&Kl[nl + dd + 6][ch * 16];
        const short8 k1 = *(const short8*)&Kl[nl + dd + 6][ch * 16 + 8];
        float s = 0.f;
        #pragma unroll
        for (int t = 0; t < 8; ++t) {
            s = fmaf(Hp[t],     b2f((unsigned short)k0[t]), s);
            s = fmaf(Hp[t + 8], b2f((unsigned short)k1[t]), s);
        }
        sacc[ch][dd][nl + 2] = s;
    }
    // halo scores (4 columns x 16 r-chunks by the 64 doubled threads)
    if (tid < 64) {
        const int ch2 = tid >> 2;
        #pragma unroll
        for (int dd = 0; dd < 5; ++dd) {
            const short8 k0 = *(const short8*)&Kl[jx + dd + 4][ch2 * 16];
            const short8 k1 = *(const short8*)&Kl[jx + dd + 4][ch2 * 16 + 8];
            float s = 0.f;
            #pragma unroll
            for (int t = 0; t < 8; ++t) {
                s = fmaf(He[t],     b2f((unsigned short)k0[t]), s);
                s = fmaf(He[t + 8], b2f((unsigned short)k1[t]), s);
            }
            sacc[ch2][dd][jx] = s;
        }
    }
    __syncthreads();   // B3

    // ---- P4: reduce over r-chunks, exp ----
    if (tid < 180) {
        const int dd = tid / 36, j = tid - dd * 36;
        float s = 0.f;
        #pragma unroll
        for (int c2 = 0; c2 < 16; ++c2) s += sacc[c2][dd][j];
        const int m = n0 + j + dd - 4;               // attended column
        se[dd][j] = (m >= 0 && m < N_DIM) ? expf(s) - 1.0f : 0.f;
    }
    __syncthreads();   // B4
    // ---- P5: denominators ----
    if (tid < 36) {
        float D = (float)N_DIM + se[0][tid] + se[1][tid] + se[2][tid]
                               + se[3][tid] + se[4][tid];
        sw[tid] = 1.0f / D;
    }
    __syncthreads();   // B5
    // ---- P6: band weights by OUTPUT column ----
    if (tid < 180) {
        const int dd = tid / 36, j = tid - dd * 36;
        const int mloc = j + dd - 4;
        if (mloc >= 0 && mloc < 32) {
            const int ncol = n0 + j - 2;             // score row n
            float v = (ncol >= 0 && ncol < N_DIM) ? se[dd][j] * sw[j] : 0.f;
            ew[4 - dd][mloc] = v;
        }
    }
    __syncthreads();   // B6

    // ---- P7: epilogue.  thread -> (c = tid>>1, half m-range of 16) ----
    {
        const int cx = tid >> 1, half = tid & 1;
        const int s0 = half * 16 + 6;                // first needed nloc
        float vv[20];
        #pragma unroll
        for (int k = 0; k < 20; ++k)
            vv[k] = b2f(AB[s0 + k][cx]);

        // partial colsum: sum_{n in half-tile} v[c][n] / D[n]
        float sp = 0.f;
        #pragma unroll
        for (int t = 0; t < 16; ++t)
            sp = fmaf(vv[t + 2], sw[half * 16 + t + 2], sp);
        sp += __shfl_xor(sp, 1, 64);
        if (half == 0)
            Sp[((size_t)b * NBLK + blockIdx.x) * C_DIM + cx] = sp;

        const float* xr   = X   + ((size_t)(b * C_DIM + cx)) * N_DIM + n0 + half * 16;
        float*       orow = Out + ((size_t)(b * C_DIM + cx)) * N_DIM + n0 + half * 16;
        #pragma unroll
        for (int g = 0; g < 4; ++g) {
            const float4 x = *(const float4*)(xr + g * 4);
            const f32x4 e0 = *(const f32x4*)&ew[0][half * 16 + g * 4];
            const f32x4 e1 = *(const f32x4*)&ew[1][half * 16 + g * 4];
            const f32x4 e2 = *(const f32x4*)&ew[2][half * 16 + g * 4];
            const f32x4 e3 = *(const f32x4*)&ew[3][half * 16 + g * 4];
            const f32x4 e4 = *(const f32x4*)&ew[4][half * 16 + g * 4];
            float4 r;
            r.x = x.x + vv[g*4+0]*e0[0] + vv[g*4+1]*e1[0] + vv[g*4+2]*e2[0]
                      + vv[g*4+3]*e3[0] + vv[g*4+4]*e4[0];
            r.y = x.y + vv[g*4+1]*e0[1] + vv[g*4+2]*e1[1] + vv[g*4+3]*e2[1]
                      + vv[g*4+4]*e3[1] + vv[g*4+5]*e4[1];
            r.z = x.z + vv[g*4+2]*e0[2] + vv[g*4+3]*e1[2] + vv[g*4+4]*e2[2]
                      + vv[g*4+5]*e3[2] + vv[g*4+6]*e4[2];
            r.w = x.w + vv[g*4+3]*e0[3] + vv[g*4+4]*e1[3] + vv[g*4+5]*e2[3]
                      + vv[g*4+6]*e3[3] + vv[g*4+7]*e4[3];
            *(float4*)(orow + g * 4) = r;
        }
    }
}

// ---------------------------------------------------------------------------
// addS: S[b][c] = sum_blk Sp;  Out[b][c][:] += S.   Out is L3-hot.
// ---------------------------------------------------------------------------
__global__ __launch_bounds__(256) void addS(
    const float* __restrict__ Sp, float* __restrict__ Out)
{
    __shared__ float sd[128];
    __shared__ float Sv;
    const int c = blockIdx.x, b = blockIdx.y;
    const int t = threadIdx.x;
    if (t < 128) sd[t] = Sp[((size_t)b * NBLK + t) * C_DIM + c];
    __syncthreads();
    if (t < 64) {
        float v = sd[t] + sd[t + 64];
        #pragma unroll
        for (int off = 32; off > 0; off >>= 1)
            v += __shfl_down(v, off, 64);
        if (t == 0) Sv = v;
    }
    __syncthreads();
    const float S = Sv;
    float* orow = Out + ((size_t)b * C_DIM + c) * N_DIM;
    #pragma unroll
    for (int it = 0; it < 4; ++it) {
        float4 o = *(const float4*)(orow + (it * 256 + t) * 4);
        o.x += S; o.y += S; o.z += S; o.w += S;
        *(float4*)(orow + (it * 256 + t) * 4) = o;
    }
}

// ---------------------------------------------------------------------------
extern "C" void kernel_launch(void* const* d_in, const int* in_sizes, int n_in,
                              void* d_out, int out_size, void* d_ws, size_t ws_size,
                              hipStream_t stream)
{
    const float* X  = (const float*)d_in[0];   // [B,C,N]
    const float* H  = (const float*)d_in[1];   // [B,R,N]
    const float* Wk = (const float*)d_in[2];   // [R,C]
    const float* Wv = (const float*)d_in[3];   // [C,C]
    float* out = (float*)d_out;

    unsigned short* Wkb = (unsigned short*)d_ws;        // 65536 shorts
    unsigned short* Wvb = Wkb + 65536;                  // 65536 shorts
    float* Sp = (float*)(Wvb + 65536);                  // [B][NBLK][C]

    castW<<<64, 256, 0, stream>>>(Wk, Wv, Wkb, Wvb);
    kvsb<<<dim3(NBLK, B_DIM), 512, 0, stream>>>(X, Wkb, Wvb, H, out, Sp);
    addS<<<dim3(C_DIM, B_DIM), 256, 0, stream>>>(Sp, out);
}